// Round 19
// baseline (139.052 us; speedup 1.0000x reference)
//
#include <hip/hip_runtime.h>
#include <hip/hip_bf16.h>
#include <math.h>

#define L 128
#define B 4
#define H 768
#define LN_EPS 1e-5f
#define XROWS 272            // xb16 rows: [p1:0..127 | unused | pg:256 | tail]

typedef __attribute__((ext_vector_type(8))) short short8;
typedef __attribute__((ext_vector_type(4))) float f32x4;

static __device__ __forceinline__ unsigned f2bfu(float f) {
    unsigned u = __float_as_uint(f);
    return (u + 0x7FFFu + ((u >> 16) & 1u)) >> 16;
}
static __device__ __forceinline__ uint2 pk4(float4 v) {
    uint2 o;
    o.x = f2bfu(v.x) | (f2bfu(v.y) << 16);
    o.y = f2bfu(v.z) | (f2bfu(v.w) << 16);
    return o;
}
static __device__ __forceinline__ unsigned short f2b(float f) {
    union { __hip_bfloat16 h; unsigned short u; } cv;
    cv.h = __float2bfloat16(f);
    return cv.u;
}
static __device__ __forceinline__ float b2f(unsigned short u) {
    return __uint_as_float(((unsigned)u) << 16);
}
static __device__ __forceinline__ unsigned fkey(float x) {
    unsigned u = __float_as_uint(x);
    return (u >> 31) ? ~u : (u | 0x80000000u);
}

// ---------------------------------------------------------------------------
// kConv: all fp32->bf16 packing, coalesced READS + scattered 16B writes.
// ---------------------------------------------------------------------------
__global__ __launch_bounds__(256) void kConv(const float* __restrict__ h_re,
                                             const float* __restrict__ h_share,
                                             const float* __restrict__ r_w,
                                             const float* __restrict__ hid_w,
                                             const float* __restrict__ rel_w,
                                             unsigned short* __restrict__ apack,
                                             unsigned short* __restrict__ wpackA,
                                             unsigned short* __restrict__ wpackB,
                                             unsigned short* __restrict__ rwb16,
                                             unsigned int* __restrict__ gmax) {
    int t = blockIdx.x * 256 + threadIdx.x;
    if (t >= 397056) return;
    if (t < 98304) {                          // apack: Acat=[h_share|h_re]
        int m = t / 192, oct = t % 192, k = oct * 8;
        const float* src = (k < 768) ? (h_share + (size_t)m * 768 + k)
                                     : (h_re + (size_t)m * 768 + k - 768);
        float4 x = *(const float4*)src, y = *(const float4*)(src + 4);
        int mt = m >> 4, lr = m & 15, ks = k >> 5, lq = (k >> 3) & 3;
        uint2* dst = (uint2*)(apack + (((size_t)mt * 48 + ks) * 64 + lq * 16 + lr) * 8);
        dst[0] = pk4(x); dst[1] = pk4(y);
    } else if (t < 245760) {                  // wpackA: r_w rows
        int t2 = t - 98304;
        int n = t2 / 192, oct = t2 % 192, k = oct * 8;
        const float* src = r_w + (size_t)n * 1536 + k;
        float4 x = *(const float4*)src, y = *(const float4*)(src + 4);
        int nt = n >> 4, lr = n & 15, ks = k >> 5, lq = (k >> 3) & 3;
        uint2* dst = (uint2*)(wpackA + (((size_t)nt * 48 + ks) * 64 + lq * 16 + lr) * 8);
        dst[0] = pk4(x); dst[1] = pk4(y);
    } else if (t < 393216) {                  // wpackB: hid_w rows (w1|w2)
        int t3 = t - 245760;
        int n = t3 / 96, oct = t3 % 96, k = oct * 8;
        int half = (n >= 768) ? 1 : 0;
        const float* src = hid_w + (size_t)(n - half * 768) * 2304 + half * 768 + k;
        float4 x = *(const float4*)src, y = *(const float4*)(src + 4);
        int nt = n >> 4, lr = n & 15, ks = k >> 5, lq = (k >> 3) & 3;
        uint2* dst = (uint2*)(wpackB + (((size_t)nt * 24 + ks) * 64 + lq * 16 + lr) * 8);
        dst[0] = pk4(x); dst[1] = pk4(y);
    } else if (t < 396288) {                  // rwb16 B-frags (16x16x32), zero-pad r>=24
        int t4 = t - 393216;
        int nt = t4 / 1536, ks = (t4 / 64) % 24, l = t4 & 63;
        int row = nt * 16 + (l & 15);
        int k = ks * 32 + (l >> 4) * 8;
        uint2 o0 = make_uint2(0u, 0u), o1 = o0;
        if (row < 24) {
            const float* src = rel_w + (size_t)row * 768 + k;
            o0 = pk4(*(const float4*)src);
            o1 = pk4(*(const float4*)(src + 4));
        }
        uint2* dst = (uint2*)(rwb16 + (size_t)t4 * 8);
        dst[0] = o0; dst[1] = o1;
    } else {                                  // gmax zero (768 scalars)
        int t6 = t - 396288;
        gmax[t6] = 0u;
        gmax[768 + t6] = 0u;
        gmax[1536 + t6] = 0u;
        gmax[2304 + t6] = 0u;
    }
}

// ---------------------------------------------------------------------------
// gemm_steps: shared MFMA inner loop (frag-linear operands, stride 512/step).
// ---------------------------------------------------------------------------
template<int KSW>
static __device__ __forceinline__ void gemm_steps(const unsigned short* __restrict__ a0p,
                                                  const unsigned short* __restrict__ a1p,
                                                  const unsigned short* __restrict__ w0p,
                                                  const unsigned short* __restrict__ w1p,
                                                  f32x4 acc[2][2]) {
#pragma unroll
    for (int s = 0; s < KSW; s++) {
        short8 a0 = *(const short8*)(a0p + (size_t)s * 512);
        short8 a1 = *(const short8*)(a1p + (size_t)s * 512);
        short8 w0 = *(const short8*)(w0p + (size_t)s * 512);
        short8 w1 = *(const short8*)(w1p + (size_t)s * 512);
        acc[0][0] = __builtin_amdgcn_mfma_f32_16x16x32_bf16(a0, w0, acc[0][0], 0, 0, 0);
        acc[0][1] = __builtin_amdgcn_mfma_f32_16x16x32_bf16(a0, w1, acc[0][1], 0, 0, 0);
        acc[1][0] = __builtin_amdgcn_mfma_f32_16x16x32_bf16(a1, w0, acc[1][0], 0, 0, 0);
        acc[1][1] = __builtin_amdgcn_mfma_f32_16x16x32_bf16(a1, w1, acc[1][1], 0, 0, 0);
    }
}

// ---------------------------------------------------------------------------
// kGemm: 4-wave blocks, one 32x32 tile, K split 4 ways, LDS reduce (r13).
// B-part epilogue: p2 -> vpack (A-frag layout); p1 -> xb16 row-major AND
// p1pack (frag layout, for kDotS).
// ---------------------------------------------------------------------------
__global__ __launch_bounds__(256) void kGemm(const unsigned short* __restrict__ apack,
                                             const unsigned short* __restrict__ wpackA,
                                             const unsigned short* __restrict__ wpackB,
                                             unsigned int* __restrict__ gmax,
                                             unsigned short* __restrict__ xb16,
                                             unsigned short* __restrict__ vpack,
                                             unsigned short* __restrict__ p1pack) {
    __shared__ float red[4][4][64][4];        // 16 KB
    int id = blockIdx.x;
    int tid = threadIdx.x, lane = tid & 63, wv = tid >> 6;
    int lq = lane >> 4, lr = lane & 15;
    bool isA = id < 384;
    f32x4 acc[2][2] = {{{0.f,0.f,0.f,0.f},{0.f,0.f,0.f,0.f}},
                       {{0.f,0.f,0.f,0.f},{0.f,0.f,0.f,0.f}}};
    int mt0, nt0;
    if (isA) {
        mt0 = (id / 24) * 2; nt0 = (id % 24) * 2;
        const unsigned short* a0p = apack + ((size_t)mt0 * 48 + wv * 12) * 512 + lane * 8;
        const unsigned short* w0p = wpackA + ((size_t)nt0 * 48 + wv * 12) * 512 + lane * 8;
        gemm_steps<12>(a0p, a0p + 48 * 512, w0p, w0p + 48 * 512, acc);
    } else {
        int id2 = id - 384;
        mt0 = (id2 / 48) * 2; nt0 = (id2 % 48) * 2;
        const unsigned short* a0p = apack + ((size_t)mt0 * 48 + 24 + wv * 6) * 512 + lane * 8;
        const unsigned short* w0p = wpackB + ((size_t)nt0 * 24 + wv * 6) * 512 + lane * 8;
        gemm_steps<6>(a0p, a0p + 48 * 512, w0p, w0p + 24 * 512, acc);
    }
#pragma unroll
    for (int mi = 0; mi < 2; mi++)
#pragma unroll
        for (int ni = 0; ni < 2; ni++)
            *(f32x4*)&red[wv][mi * 2 + ni][lane][0] = acc[mi][ni];
    __syncthreads();
    if (wv != 0) return;

    f32x4 s2[2][2];
#pragma unroll
    for (int mi = 0; mi < 2; mi++)
#pragma unroll
        for (int ni = 0; ni < 2; ni++) {
            f32x4 v = *(f32x4*)&red[0][mi * 2 + ni][lane][0];
#pragma unroll
            for (int w = 1; w < 4; w++) {
                f32x4 u = *(f32x4*)&red[w][mi * 2 + ni][lane][0];
                v[0] += u[0]; v[1] += u[1]; v[2] += u[2]; v[3] += u[3];
            }
            s2[mi][ni] = v;
        }

    if (isA) {
#pragma unroll
        for (int ni = 0; ni < 2; ni++)
#pragma unroll
            for (int q = 0; q < 4; q++) {
                float mx = fmaxf(s2[0][ni][q], s2[1][ni][q]);
                mx = fmaxf(mx, __shfl_xor(mx, 16, 64));
                mx = fmaxf(mx, __shfl_xor(mx, 32, 64));
                if (lq == 0) {
                    int n = (nt0 + ni) * 16 + lr;
                    atomicMax(&gmax[q * 768 + n], fkey(mx));
                }
            }
    } else {
#pragma unroll
        for (int mi = 0; mi < 2; mi++)
#pragma unroll
            for (int ni = 0; ni < 2; ni++)
#pragma unroll
                for (int q = 0; q < 4; q++) {
                    int m = (mt0 + mi) * 16 + lq * 4 + q;
                    int n = (nt0 + ni) * 16 + lr;
                    int b = m & 3, l = m >> 2;
                    unsigned short val = f2b(s2[mi][ni][q]);
                    if (n < 768) {
                        xb16[((size_t)b * XROWS + l) * 768 + n] = val;
                        size_t dst = ((((size_t)(b * 8 + (l >> 4)) * 24) + (n >> 5)) * 64
                                      + ((n >> 3) & 3) * 16 + (l & 15)) * 8 + (n & 7);
                        p1pack[dst] = val;
                    } else {
                        int k = n - 768;
                        size_t dst = ((((size_t)(b * 8 + (l >> 4)) * 24) + (k >> 5)) * 64
                                      + ((k >> 3) & 3) * 16 + (l & 15)) * 8 + (k & 7);
                        vpack[dst] = val;
                    }
                }
    }
}

// ---------------------------------------------------------------------------
// kDotS: blocks 0..63: Dp[b][i][j] = dot(p1_i, v_j) via MFMA (32x32 tiles,
// K split 4 waves, LDS reduce). blocks 64..79: per-row sums/sumsq of p1 and v
// (coalesced frag reads + 2-shfl reduce; 4 lanes share a row).
// ---------------------------------------------------------------------------
__global__ __launch_bounds__(256) void kDotS(const unsigned short* __restrict__ p1pack,
                                             const unsigned short* __restrict__ vpack,
                                             float* __restrict__ Dp,
                                             float* __restrict__ Sp1,
                                             float* __restrict__ Sp1q,
                                             float* __restrict__ Sv1,
                                             float* __restrict__ Sv2) {
    __shared__ float red[4][4][64][4];
    int id = blockIdx.x;
    int tid = threadIdx.x, lane = tid & 63, wv = tid >> 6;
    int lq = lane >> 4, lr = lane & 15;
    if (id < 64) {
        int b = id >> 4, tile = id & 15, it = tile >> 2, jt = tile & 3;
        f32x4 acc[2][2] = {{{0.f,0.f,0.f,0.f},{0.f,0.f,0.f,0.f}},
                           {{0.f,0.f,0.f,0.f},{0.f,0.f,0.f,0.f}}};
        const unsigned short* a0p = p1pack + (((size_t)(b * 8 + it * 2) * 24) + wv * 6) * 512 + lane * 8;
        const unsigned short* a1p = p1pack + (((size_t)(b * 8 + it * 2 + 1) * 24) + wv * 6) * 512 + lane * 8;
        const unsigned short* w0p = vpack + (((size_t)(b * 8 + jt * 2) * 24) + wv * 6) * 512 + lane * 8;
        const unsigned short* w1p = vpack + (((size_t)(b * 8 + jt * 2 + 1) * 24) + wv * 6) * 512 + lane * 8;
        gemm_steps<6>(a0p, a1p, w0p, w1p, acc);
#pragma unroll
        for (int mi = 0; mi < 2; mi++)
#pragma unroll
            for (int ni = 0; ni < 2; ni++)
                *(f32x4*)&red[wv][mi * 2 + ni][lane][0] = acc[mi][ni];
        __syncthreads();
        if (wv != 0) return;
#pragma unroll
        for (int mi = 0; mi < 2; mi++)
#pragma unroll
            for (int ni = 0; ni < 2; ni++) {
                f32x4 v = *(f32x4*)&red[0][mi * 2 + ni][lane][0];
#pragma unroll
                for (int w = 1; w < 4; w++) {
                    f32x4 u = *(f32x4*)&red[w][mi * 2 + ni][lane][0];
                    v[0] += u[0]; v[1] += u[1]; v[2] += u[2]; v[3] += u[3];
                }
#pragma unroll
                for (int q = 0; q < 4; q++) {
                    int i = it * 32 + mi * 16 + lq * 4 + q;
                    int j = jt * 32 + ni * 16 + lr;
                    Dp[((size_t)b * 128 + i) * 128 + j] = v[q];
                }
            }
    } else {
        int t = (id - 64) * 4 + wv;            // 0..63
        bool isP = t < 32;
        int t2 = t & 31;
        int b = t2 >> 3, tile = t2 & 7;
        const unsigned short* src = (isP ? p1pack : vpack)
                                    + ((size_t)(b * 8 + tile) * 24) * 512 + lane * 8;
        float s1 = 0.f, sq = 0.f;
        for (int s = 0; s < 24; s++) {
            uint4 x = *(const uint4*)(src + (size_t)s * 512);
            const unsigned* xw = (const unsigned*)&x;
#pragma unroll
            for (int h = 0; h < 4; h++) {
                float e0 = __uint_as_float(xw[h] << 16);
                float e1 = __uint_as_float(xw[h] & 0xffff0000u);
                s1 += e0 + e1;
                sq = fmaf(e0, e0, fmaf(e1, e1, sq));
            }
        }
        s1 += __shfl_xor(s1, 16, 64); s1 += __shfl_xor(s1, 32, 64);
        sq += __shfl_xor(sq, 16, 64); sq += __shfl_xor(sq, 32, 64);
        if (lq == 0) {
            int row = tile * 16 + lr;
            if (isP) { Sp1[b * 128 + row] = s1; Sp1q[b * 128 + row] = sq; }
            else     { Sv1[b * 128 + row] = s1; Sv2[b * 128 + row] = sq; }
        }
    }
}

// ---------------------------------------------------------------------------
// kPgX: per-b block (grid 4): decode gmax -> g=tanh; pg GEMM; write pg bf16;
// Spg/Spg2 from the bf16-rounded pg; cross dots Cp1[i]=dot(pg,p1_i),
// Cv[j]=dot(pg,v_j) via coalesced frag reads.
// ---------------------------------------------------------------------------
__global__ __launch_bounds__(256) void kPgX(const unsigned int* __restrict__ gmax,
                                            const float* __restrict__ r_b,
                                            const float* __restrict__ hid_w,
                                            const float* __restrict__ hid_b,
                                            const unsigned short* __restrict__ p1pack,
                                            const unsigned short* __restrict__ vpack,
                                            unsigned short* __restrict__ xb16,
                                            float* __restrict__ Spg,
                                            float* __restrict__ Spg2,
                                            float* __restrict__ Cp1,
                                            float* __restrict__ Cv) {
    __shared__ float sg[768];
    __shared__ float spg[768];
    __shared__ float rbuf[8];
    int b = blockIdx.x, tid = threadIdx.x;
    int lane = tid & 63, wv = tid >> 6, lq = lane >> 4, lr = lane & 15;

    for (int v = tid; v < 768; v += 256) {
        unsigned key = gmax[b * 768 + v];
        unsigned bits = (key & 0x80000000u) ? (key & 0x7FFFFFFFu) : ~key;
        sg[v] = tanhf(__uint_as_float(bits) + r_b[v]);
    }
    __syncthreads();
    const float4* w4 = (const float4*)hid_w;
    const float4* g4 = (const float4*)sg;
#pragma unroll
    for (int kk = 0; kk < 3; kk++) {
        int k = tid + kk * 256;
        float acc = 0.f;
        for (int h = 0; h < 192; h++) {
            float4 gv = g4[h];
            float4 ww = w4[(size_t)k * 576 + 384 + h];
            acc += gv.x * ww.x + gv.y * ww.y + gv.z * ww.z + gv.w * ww.w;
        }
        unsigned short pb = f2b(acc + hid_b[k]);
        xb16[((size_t)b * XROWS + 256) * 768 + k] = pb;
        spg[k] = b2f(pb);
    }
    __syncthreads();
    // Spg / Spg2 (from bf16-rounded values)
    float l1 = 0.f, l2 = 0.f;
    for (int v = tid; v < 768; v += 256) { float x = spg[v]; l1 += x; l2 = fmaf(x, x, l2); }
#pragma unroll
    for (int off = 32; off > 0; off >>= 1) {
        l1 += __shfl_xor(l1, off, 64);
        l2 += __shfl_xor(l2, off, 64);
    }
    if (lane == 0) { rbuf[wv] = l1; rbuf[4 + wv] = l2; }
    __syncthreads();
    if (tid == 0) {
        Spg[b]  = rbuf[0] + rbuf[1] + rbuf[2] + rbuf[3];
        Spg2[b] = rbuf[4] + rbuf[5] + rbuf[6] + rbuf[7];
    }
    // cross dots: 16 groups (8 p1-tiles, 8 v-tiles), 4 per wave
    for (int gi = 0; gi < 4; gi++) {
        int g = wv + gi * 4;                   // 0..15
        int side = g >> 3, tile = g & 7;
        const unsigned short* src = (side ? vpack : p1pack)
                                    + ((size_t)(b * 8 + tile) * 24) * 512 + lane * 8;
        float d = 0.f;
        for (int s = 0; s < 24; s++) {
            uint4 x = *(const uint4*)(src + (size_t)s * 512);
            const unsigned* xw = (const unsigned*)&x;
            int kb = s * 32 + lq * 8;
#pragma unroll
            for (int h = 0; h < 4; h++) {
                float e0 = __uint_as_float(xw[h] << 16);
                float e1 = __uint_as_float(xw[h] & 0xffff0000u);
                d = fmaf(e0, spg[kb + 2 * h], fmaf(e1, spg[kb + 2 * h + 1], d));
            }
        }
        d += __shfl_xor(d, 16, 64); d += __shfl_xor(d, 32, 64);
        if (lq == 0) {
            int row = tile * 16 + lr;
            if (side) Cv[b * 128 + row] = d;
            else      Cp1[b * 128 + row] = d;
        }
    }
}

// ---------------------------------------------------------------------------
// kC v6: pass-2 only. Stats assembled from decomposed terms (9 scalar loads
// per lane). Zero LDS/barriers; 1-wave blocks, grid (128,4,8).
// ---------------------------------------------------------------------------
__global__ __launch_bounds__(64, 4) void kC(const unsigned short* __restrict__ xb16,
                                            const unsigned short* __restrict__ vpack,
                                            const float* __restrict__ ln_g,
                                            const float* __restrict__ ln_b,
                                            const unsigned short* __restrict__ rwb16,
                                            const float* __restrict__ rel_b,
                                            const float* __restrict__ mask,
                                            const float* __restrict__ Dp,
                                            const float* __restrict__ Sp1,
                                            const float* __restrict__ Sp1q,
                                            const float* __restrict__ Sv1,
                                            const float* __restrict__ Sv2,
                                            const float* __restrict__ Spg,
                                            const float* __restrict__ Spg2,
                                            const float* __restrict__ Cp1,
                                            const float* __restrict__ Cv,
                                            float* __restrict__ out) {
    int i = blockIdx.x, b = blockIdx.y, jg = blockIdx.z;
    int lane = threadIdx.x;
    int lr = lane & 15, lh = lane >> 4;
    int j = jg * 16 + lr;

    // stats for row (i, j, b) — my lane's A-frag row is lr
    float s1 = Sp1[b * 128 + i] + Spg[b] + Sv1[b * 128 + j];
    float s2 = Sp1q[b * 128 + i] + Spg2[b] + Sv2[b * 128 + j]
             + 2.f * (Dp[((size_t)b * 128 + i) * 128 + j]
                      + Cp1[b * 128 + i] + Cv[b * 128 + j]);
    float mu  = s1 * (1.f / 768.f);
    float rs  = rsqrtf(s2 * (1.f / 768.f) - mu * mu + LN_EPS);
    float nmr = -mu * rs;

    const unsigned short* p1r = xb16 + ((size_t)b * XROWS + i) * 768;
    const unsigned short* pgr = xb16 + ((size_t)b * XROWS + 256) * 768;
    const unsigned short* vfr = vpack + (((size_t)(b * 8 + jg) * 24) * 64 + (size_t)lane) * 8;

    f32x4 acc0 = {0.f, 0.f, 0.f, 0.f}, acc1 = {0.f, 0.f, 0.f, 0.f};
#pragma unroll 2
    for (int s = 0; s < 24; s++) {
        int k = s * 32 + lh * 8;
        uint4 vv = *(const uint4*)(vfr + (size_t)s * 512);
        uint4 uu = *(const uint4*)(p1r + k);
        uint4 pp = *(const uint4*)(pgr + k);
        float4 g0 = *(const float4*)(ln_g + k), g1 = *(const float4*)(ln_g + k + 4);
        float4 b0 = *(const float4*)(ln_b + k), b1 = *(const float4*)(ln_b + k + 4);
        const unsigned* vw = (const unsigned*)&vv;
        const unsigned* uw = (const unsigned*)&uu;
        const unsigned* pw = (const unsigned*)&pp;
        float ge[8] = {g0.x, g0.y, g0.z, g0.w, g1.x, g1.y, g1.z, g1.w};
        float be[8] = {b0.x, b0.y, b0.z, b0.w, b1.x, b1.y, b1.z, b1.w};
        short8 a;
#pragma unroll
        for (int h = 0; h < 4; h++) {
            float z0 = __uint_as_float(vw[h] << 16) + __uint_as_float(uw[h] << 16)
                     + __uint_as_float(pw[h] << 16);
            float z1 = __uint_as_float(vw[h] & 0xffff0000u) + __uint_as_float(uw[h] & 0xffff0000u)
                     + __uint_as_float(pw[h] & 0xffff0000u);
            float t0 = fmaf(fmaf(z0, rs, nmr), ge[2 * h], be[2 * h]);
            float t1 = fmaf(fmaf(z1, rs, nmr), ge[2 * h + 1], be[2 * h + 1]);
            t0 = fmaxf(t0, __expf(fminf(t0, 0.f)) - 1.f);
            t1 = fmaxf(t1, __expf(fminf(t1, 0.f)) - 1.f);
            a[2 * h]     = (short)f2b(t0);
            a[2 * h + 1] = (short)f2b(t1);
        }
        short8 bf0 = *(const short8*)(rwb16 + ((size_t)s * 64 + lane) * 8);
        short8 bf1 = *(const short8*)(rwb16 + ((size_t)(24 + s) * 64 + lane) * 8);
        acc0 = __builtin_amdgcn_mfma_f32_16x16x32_bf16(a, bf0, acc0, 0, 0, 0);
        acc1 = __builtin_amdgcn_mfma_f32_16x16x32_bf16(a, bf1, acc1, 0, 0, 0);
    }

    float mi_ = mask[i * 4 + b];
#pragma unroll
    for (int q = 0; q < 4; q++) {
        int jglob = jg * 16 + lh * 4 + q;
        float mval = mi_ * mask[jglob * 4 + b];
        size_t ob = ((size_t)(i * 128 + jglob) * 4 + b) * 24;
        out[ob + lr] = mval / (1.f + __expf(-(acc0[q] + rel_b[lr])));
        if (lr < 8)
            out[ob + 16 + lr] = mval / (1.f + __expf(-(acc1[q] + rel_b[16 + lr])));
    }
}

// ---------------------------------------------------------------------------
extern "C" void kernel_launch(void* const* d_in, const int* in_sizes, int n_in,
                              void* d_out, int out_size, void* d_ws, size_t ws_size,
                              hipStream_t stream) {
    const float* h_re    = (const float*)d_in[0];
    const float* h_share = (const float*)d_in[1];
    const float* mask    = (const float*)d_in[2];
    const float* r_w     = (const float*)d_in[3];
    const float* r_b     = (const float*)d_in[4];
    const float* hid_w   = (const float*)d_in[5];
    const float* hid_b   = (const float*)d_in[6];
    const float* ln_g    = (const float*)d_in[7];
    const float* ln_b    = (const float*)d_in[8];
    const float* rel_w   = (const float*)d_in[9];
    const float* rel_b   = (const float*)d_in[10];
    float* out = (float*)d_out;

    float* ws = (float*)d_ws;
    unsigned short* apack  = (unsigned short*)(ws);             // 393216 f
    unsigned short* wpackA = (unsigned short*)(ws + 393216);    // 589824 f
    unsigned short* wpackB = (unsigned short*)(ws + 983040);    // 589824 f
    unsigned short* xb16   = (unsigned short*)(ws + 1572864);   // 417792 f
    unsigned short* vpack  = (unsigned short*)(ws + 1990656);   // 196608 f
    unsigned short* p1pack = (unsigned short*)(ws + 2187264);   // 196608 f
    float*          Dp     = ws + 2383872;                      // 65536 f
    unsigned int*   gmax   = (unsigned int*)(ws + 2449408);     // 3072
    unsigned short* rwb16  = (unsigned short*)(ws + 2452480);   // 12288 f
    float*          Sp1    = ws + 2464768;                      // 512
    float*          Sp1q   = ws + 2465280;                      // 512
    float*          Sv1    = ws + 2465792;                      // 512
    float*          Sv2    = ws + 2466304;                      // 512
    float*          Cp1    = ws + 2466816;                      // 512
    float*          Cv     = ws + 2467328;                      // 512
    float*          SpgB   = ws + 2467840;                      // 4
    float*          Spg2B  = ws + 2467844;                      // 4

    kConv<<<1552, 256, 0, stream>>>(h_re, h_share, r_w, hid_w, rel_w,
                                    apack, wpackA, wpackB, rwb16, gmax);
    kGemm<<<1152, 256, 0, stream>>>(apack, wpackA, wpackB, gmax, xb16,
                                    vpack, p1pack);
    kDotS<<<80, 256, 0, stream>>>(p1pack, vpack, Dp, Sp1, Sp1q, Sv1, Sv2);
    kPgX<<<4, 256, 0, stream>>>(gmax, r_b, hid_w, hid_b, p1pack, vpack,
                                xb16, SpgB, Spg2B, Cp1, Cv);
    kC<<<dim3(128, 4, 8), 64, 0, stream>>>(xb16, vpack, ln_g, ln_b, rwb16,
                                           rel_b, mask, Dp, Sp1, Sp1q,
                                           Sv1, Sv2, SpgB, Spg2B, Cp1, Cv, out);
}

// Round 20
// 70.445 us; speedup vs baseline: 1.9739x; 1.9739x over previous
//
#include <hip/hip_runtime.h>
#include <hip/hip_bf16.h>
#include <math.h>

#define L 128
#define B 4
#define H 768
#define LN_EPS 1e-5f
#define XROWS 272            // xb16 rows: [p1:0..127 | unused | pg:256 | tail]

typedef __attribute__((ext_vector_type(8))) short short8;
typedef __attribute__((ext_vector_type(4))) float f32x4;

static __device__ __forceinline__ unsigned f2bfu(float f) {
    unsigned u = __float_as_uint(f);
    return (u + 0x7FFFu + ((u >> 16) & 1u)) >> 16;
}
static __device__ __forceinline__ uint2 pk4(float4 v) {
    uint2 o;
    o.x = f2bfu(v.x) | (f2bfu(v.y) << 16);
    o.y = f2bfu(v.z) | (f2bfu(v.w) << 16);
    return o;
}
static __device__ __forceinline__ unsigned short f2b(float f) {
    union { __hip_bfloat16 h; unsigned short u; } cv;
    cv.h = __float2bfloat16(f);
    return cv.u;
}
static __device__ __forceinline__ unsigned fkey(float x) {
    unsigned u = __float_as_uint(x);
    return (u >> 31) ? ~u : (u | 0x80000000u);
}

// ---------------------------------------------------------------------------
// kConv: all fp32->bf16 packing, coalesced READS + scattered 16B writes.
// ---------------------------------------------------------------------------
__global__ __launch_bounds__(256) void kConv(const float* __restrict__ h_re,
                                             const float* __restrict__ h_share,
                                             const float* __restrict__ r_w,
                                             const float* __restrict__ hid_w,
                                             const float* __restrict__ rel_w,
                                             unsigned short* __restrict__ apack,
                                             unsigned short* __restrict__ wpackA,
                                             unsigned short* __restrict__ wpackB,
                                             unsigned short* __restrict__ rwb16,
                                             unsigned int* __restrict__ gmax) {
    int t = blockIdx.x * 256 + threadIdx.x;
    if (t >= 397056) return;
    if (t < 98304) {                          // apack: Acat=[h_share|h_re]
        int m = t / 192, oct = t % 192, k = oct * 8;
        const float* src = (k < 768) ? (h_share + (size_t)m * 768 + k)
                                     : (h_re + (size_t)m * 768 + k - 768);
        float4 x = *(const float4*)src, y = *(const float4*)(src + 4);
        int mt = m >> 4, lr = m & 15, ks = k >> 5, lq = (k >> 3) & 3;
        uint2* dst = (uint2*)(apack + (((size_t)mt * 48 + ks) * 64 + lq * 16 + lr) * 8);
        dst[0] = pk4(x); dst[1] = pk4(y);
    } else if (t < 245760) {                  // wpackA: r_w rows
        int t2 = t - 98304;
        int n = t2 / 192, oct = t2 % 192, k = oct * 8;
        const float* src = r_w + (size_t)n * 1536 + k;
        float4 x = *(const float4*)src, y = *(const float4*)(src + 4);
        int nt = n >> 4, lr = n & 15, ks = k >> 5, lq = (k >> 3) & 3;
        uint2* dst = (uint2*)(wpackA + (((size_t)nt * 48 + ks) * 64 + lq * 16 + lr) * 8);
        dst[0] = pk4(x); dst[1] = pk4(y);
    } else if (t < 393216) {                  // wpackB: hid_w rows (w1|w2)
        int t3 = t - 245760;
        int n = t3 / 96, oct = t3 % 96, k = oct * 8;
        int half = (n >= 768) ? 1 : 0;
        const float* src = hid_w + (size_t)(n - half * 768) * 2304 + half * 768 + k;
        float4 x = *(const float4*)src, y = *(const float4*)(src + 4);
        int nt = n >> 4, lr = n & 15, ks = k >> 5, lq = (k >> 3) & 3;
        uint2* dst = (uint2*)(wpackB + (((size_t)nt * 24 + ks) * 64 + lq * 16 + lr) * 8);
        dst[0] = pk4(x); dst[1] = pk4(y);
    } else if (t < 396288) {                  // rwb16 B-frags (16x16x32), zero-pad r>=24
        int t4 = t - 393216;
        int nt = t4 / 1536, ks = (t4 / 64) % 24, l = t4 & 63;
        int row = nt * 16 + (l & 15);
        int k = ks * 32 + (l >> 4) * 8;
        uint2 o0 = make_uint2(0u, 0u), o1 = o0;
        if (row < 24) {
            const float* src = rel_w + (size_t)row * 768 + k;
            o0 = pk4(*(const float4*)src);
            o1 = pk4(*(const float4*)(src + 4));
        }
        uint2* dst = (uint2*)(rwb16 + (size_t)t4 * 8);
        dst[0] = o0; dst[1] = o1;
    } else {                                  // gmax zero (768 scalars)
        int t6 = t - 396288;
        gmax[t6] = 0u;
        gmax[768 + t6] = 0u;
        gmax[1536 + t6] = 0u;
        gmax[2304 + t6] = 0u;
    }
}

// ---------------------------------------------------------------------------
// gemm_steps: shared MFMA inner loop (frag-linear operands, stride 512/step).
// ---------------------------------------------------------------------------
template<int KSW>
static __device__ __forceinline__ void gemm_steps(const unsigned short* __restrict__ a0p,
                                                  const unsigned short* __restrict__ a1p,
                                                  const unsigned short* __restrict__ w0p,
                                                  const unsigned short* __restrict__ w1p,
                                                  f32x4 acc[2][2]) {
#pragma unroll
    for (int s = 0; s < KSW; s++) {
        short8 a0 = *(const short8*)(a0p + (size_t)s * 512);
        short8 a1 = *(const short8*)(a1p + (size_t)s * 512);
        short8 w0 = *(const short8*)(w0p + (size_t)s * 512);
        short8 w1 = *(const short8*)(w1p + (size_t)s * 512);
        acc[0][0] = __builtin_amdgcn_mfma_f32_16x16x32_bf16(a0, w0, acc[0][0], 0, 0, 0);
        acc[0][1] = __builtin_amdgcn_mfma_f32_16x16x32_bf16(a0, w1, acc[0][1], 0, 0, 0);
        acc[1][0] = __builtin_amdgcn_mfma_f32_16x16x32_bf16(a1, w0, acc[1][0], 0, 0, 0);
        acc[1][1] = __builtin_amdgcn_mfma_f32_16x16x32_bf16(a1, w1, acc[1][1], 0, 0, 0);
    }
}

// ---------------------------------------------------------------------------
// kGemm: 4-wave blocks, one 32x32 tile, K split 4 ways, LDS reduce (r13).
// B-part epilogue: p2 -> vpack; p1 -> xb16 row-major AND p1pack.
// ---------------------------------------------------------------------------
__global__ __launch_bounds__(256) void kGemm(const unsigned short* __restrict__ apack,
                                             const unsigned short* __restrict__ wpackA,
                                             const unsigned short* __restrict__ wpackB,
                                             unsigned int* __restrict__ gmax,
                                             unsigned short* __restrict__ xb16,
                                             unsigned short* __restrict__ vpack,
                                             unsigned short* __restrict__ p1pack) {
    __shared__ float red[4][4][64][4];        // 16 KB
    int id = blockIdx.x;
    int tid = threadIdx.x, lane = tid & 63, wv = tid >> 6;
    int lq = lane >> 4, lr = lane & 15;
    bool isA = id < 384;
    f32x4 acc[2][2] = {{{0.f,0.f,0.f,0.f},{0.f,0.f,0.f,0.f}},
                       {{0.f,0.f,0.f,0.f},{0.f,0.f,0.f,0.f}}};
    int mt0, nt0;
    if (isA) {
        mt0 = (id / 24) * 2; nt0 = (id % 24) * 2;
        const unsigned short* a0p = apack + ((size_t)mt0 * 48 + wv * 12) * 512 + lane * 8;
        const unsigned short* w0p = wpackA + ((size_t)nt0 * 48 + wv * 12) * 512 + lane * 8;
        gemm_steps<12>(a0p, a0p + 48 * 512, w0p, w0p + 48 * 512, acc);
    } else {
        int id2 = id - 384;
        mt0 = (id2 / 48) * 2; nt0 = (id2 % 48) * 2;
        const unsigned short* a0p = apack + ((size_t)mt0 * 48 + 24 + wv * 6) * 512 + lane * 8;
        const unsigned short* w0p = wpackB + ((size_t)nt0 * 24 + wv * 6) * 512 + lane * 8;
        gemm_steps<6>(a0p, a0p + 48 * 512, w0p, w0p + 24 * 512, acc);
    }
#pragma unroll
    for (int mi = 0; mi < 2; mi++)
#pragma unroll
        for (int ni = 0; ni < 2; ni++)
            *(f32x4*)&red[wv][mi * 2 + ni][lane][0] = acc[mi][ni];
    __syncthreads();
    if (wv != 0) return;

    f32x4 s2[2][2];
#pragma unroll
    for (int mi = 0; mi < 2; mi++)
#pragma unroll
        for (int ni = 0; ni < 2; ni++) {
            f32x4 v = *(f32x4*)&red[0][mi * 2 + ni][lane][0];
#pragma unroll
            for (int w = 1; w < 4; w++) {
                f32x4 u = *(f32x4*)&red[w][mi * 2 + ni][lane][0];
                v[0] += u[0]; v[1] += u[1]; v[2] += u[2]; v[3] += u[3];
            }
            s2[mi][ni] = v;
        }

    if (isA) {
#pragma unroll
        for (int ni = 0; ni < 2; ni++)
#pragma unroll
            for (int q = 0; q < 4; q++) {
                float mx = fmaxf(s2[0][ni][q], s2[1][ni][q]);
                mx = fmaxf(mx, __shfl_xor(mx, 16, 64));
                mx = fmaxf(mx, __shfl_xor(mx, 32, 64));
                if (lq == 0) {
                    int n = (nt0 + ni) * 16 + lr;
                    atomicMax(&gmax[q * 768 + n], fkey(mx));
                }
            }
    } else {
#pragma unroll
        for (int mi = 0; mi < 2; mi++)
#pragma unroll
            for (int ni = 0; ni < 2; ni++)
#pragma unroll
                for (int q = 0; q < 4; q++) {
                    int m = (mt0 + mi) * 16 + lq * 4 + q;
                    int n = (nt0 + ni) * 16 + lr;
                    int b = m & 3, l = m >> 2;
                    unsigned short val = f2b(s2[mi][ni][q]);
                    if (n < 768) {
                        xb16[((size_t)b * XROWS + l) * 768 + n] = val;
                        size_t dst = ((((size_t)(b * 8 + (l >> 4)) * 24) + (n >> 5)) * 64
                                      + ((n >> 3) & 3) * 16 + (l & 15)) * 8 + (n & 7);
                        p1pack[dst] = val;
                    } else {
                        int k = n - 768;
                        size_t dst = ((((size_t)(b * 8 + (l >> 4)) * 24) + (k >> 5)) * 64
                                      + ((k >> 3) & 3) * 16 + (l & 15)) * 8 + (k & 7);
                        vpack[dst] = val;
                    }
                }
    }
}

// ---------------------------------------------------------------------------
// kPg (r13-proven): grid (12,4), 48 blocks. tanh decode + pg GEMM + bf16 write.
// ---------------------------------------------------------------------------
__global__ __launch_bounds__(256) void kPg(const unsigned int* __restrict__ gmax,
                                           const float* __restrict__ r_b,
                                           const float* __restrict__ hid_w,
                                           const float* __restrict__ hid_b,
                                           unsigned short* __restrict__ xb16) {
    __shared__ float sg[768];
    __shared__ float sp[4][64];
    int kt = blockIdx.x, b = blockIdx.y, tid = threadIdx.x;
    for (int v = tid; v < 768; v += 256) {
        unsigned key = gmax[b * 768 + v];
        unsigned bits = (key & 0x80000000u) ? (key & 0x7FFFFFFFu) : ~key;
        sg[v] = tanhf(__uint_as_float(bits) + r_b[v]);
    }
    __syncthreads();
    int kk = tid & 63, hc = tid >> 6;
    int k = kt * 64 + kk;
    const float4* w4 = (const float4*)hid_w;
    const float4* g4 = (const float4*)sg;
    float acc = 0.f;
    for (int h = hc * 48; h < hc * 48 + 48; h++) {
        float4 gv = g4[h];
        float4 wv = w4[(size_t)k * 576 + 384 + h];
        acc += gv.x * wv.x + gv.y * wv.y + gv.z * wv.z + gv.w * wv.w;
    }
    sp[hc][kk] = acc;
    __syncthreads();
    if (hc == 0) {
        float pgv = sp[0][kk] + sp[1][kk] + sp[2][kk] + sp[3][kk] + hid_b[k];
        xb16[((size_t)b * XROWS + 256) * 768 + k] = f2b(pgv);
    }
}

// ---------------------------------------------------------------------------
// kDotS (97 blocks, after kPg):
//  0..63 : Dp[b][i][j] = dot(p1_i, v_j) via MFMA 32x32 tiles (K/4 + LDS reduce)
//  64..79: per-row sums/sumsq of p1 and v (frag reads + 2-shfl reduce)
//  80..95: cross dots Cp1[i]=dot(pg,p1_i), Cv[j]=dot(pg,v_j) (pg bf16 from xb16)
//  96    : Spg/Spg2 per b (one wave each)
// ---------------------------------------------------------------------------
__global__ __launch_bounds__(256) void kDotS(const unsigned short* __restrict__ p1pack,
                                             const unsigned short* __restrict__ vpack,
                                             const unsigned short* __restrict__ xb16,
                                             float* __restrict__ Dp,
                                             float* __restrict__ Sp1,
                                             float* __restrict__ Sp1q,
                                             float* __restrict__ Sv1,
                                             float* __restrict__ Sv2,
                                             float* __restrict__ Cp1,
                                             float* __restrict__ Cv,
                                             float* __restrict__ Spg,
                                             float* __restrict__ Spg2) {
    __shared__ float red[4][4][64][4];
    int id = blockIdx.x;
    int tid = threadIdx.x, lane = tid & 63, wv = tid >> 6;
    int lq = lane >> 4, lr = lane & 15;
    if (id < 64) {
        int b = id >> 4, tile = id & 15, it = tile >> 2, jt = tile & 3;
        f32x4 acc[2][2] = {{{0.f,0.f,0.f,0.f},{0.f,0.f,0.f,0.f}},
                           {{0.f,0.f,0.f,0.f},{0.f,0.f,0.f,0.f}}};
        const unsigned short* a0p = p1pack + (((size_t)(b * 8 + it * 2) * 24) + wv * 6) * 512 + lane * 8;
        const unsigned short* a1p = p1pack + (((size_t)(b * 8 + it * 2 + 1) * 24) + wv * 6) * 512 + lane * 8;
        const unsigned short* w0p = vpack + (((size_t)(b * 8 + jt * 2) * 24) + wv * 6) * 512 + lane * 8;
        const unsigned short* w1p = vpack + (((size_t)(b * 8 + jt * 2 + 1) * 24) + wv * 6) * 512 + lane * 8;
        gemm_steps<6>(a0p, a1p, w0p, w1p, acc);
#pragma unroll
        for (int mi = 0; mi < 2; mi++)
#pragma unroll
            for (int ni = 0; ni < 2; ni++)
                *(f32x4*)&red[wv][mi * 2 + ni][lane][0] = acc[mi][ni];
        __syncthreads();
        if (wv != 0) return;
#pragma unroll
        for (int mi = 0; mi < 2; mi++)
#pragma unroll
            for (int ni = 0; ni < 2; ni++) {
                f32x4 v = *(f32x4*)&red[0][mi * 2 + ni][lane][0];
#pragma unroll
                for (int w = 1; w < 4; w++) {
                    f32x4 u = *(f32x4*)&red[w][mi * 2 + ni][lane][0];
                    v[0] += u[0]; v[1] += u[1]; v[2] += u[2]; v[3] += u[3];
                }
#pragma unroll
                for (int q = 0; q < 4; q++) {
                    int i = it * 32 + mi * 16 + lq * 4 + q;
                    int j = jt * 32 + ni * 16 + lr;
                    Dp[((size_t)b * 128 + i) * 128 + j] = v[q];
                }
            }
    } else if (id < 80) {
        int t = (id - 64) * 4 + wv;            // 0..63
        bool isP = t < 32;
        int t2 = t & 31;
        int b = t2 >> 3, tile = t2 & 7;
        const unsigned short* src = (isP ? p1pack : vpack)
                                    + ((size_t)(b * 8 + tile) * 24) * 512 + lane * 8;
        float s1 = 0.f, sq = 0.f;
        for (int s = 0; s < 24; s++) {
            uint4 x = *(const uint4*)(src + (size_t)s * 512);
            const unsigned* xw = (const unsigned*)&x;
#pragma unroll
            for (int h = 0; h < 4; h++) {
                float e0 = __uint_as_float(xw[h] << 16);
                float e1 = __uint_as_float(xw[h] & 0xffff0000u);
                s1 += e0 + e1;
                sq = fmaf(e0, e0, fmaf(e1, e1, sq));
            }
        }
        s1 += __shfl_xor(s1, 16, 64); s1 += __shfl_xor(s1, 32, 64);
        sq += __shfl_xor(sq, 16, 64); sq += __shfl_xor(sq, 32, 64);
        if (lq == 0) {
            int row = tile * 16 + lr;
            if (isP) { Sp1[b * 128 + row] = s1; Sp1q[b * 128 + row] = sq; }
            else     { Sv1[b * 128 + row] = s1; Sv2[b * 128 + row] = sq; }
        }
    } else if (id < 96) {
        int t = (id - 80) * 4 + wv;            // 0..63
        bool isP = t < 32;
        int t2 = t & 31;
        int b = t2 >> 3, tile = t2 & 7;
        const unsigned short* src = (isP ? p1pack : vpack)
                                    + ((size_t)(b * 8 + tile) * 24) * 512 + lane * 8;
        const unsigned short* pgr = xb16 + ((size_t)b * XROWS + 256) * 768;
        float d = 0.f;
        for (int s = 0; s < 24; s++) {
            int kb = s * 32 + lq * 8;
            uint4 x = *(const uint4*)(src + (size_t)s * 512);
            uint4 p = *(const uint4*)(pgr + kb);
            const unsigned* xw = (const unsigned*)&x;
            const unsigned* pw = (const unsigned*)&p;
#pragma unroll
            for (int h = 0; h < 4; h++) {
                float e0 = __uint_as_float(xw[h] << 16);
                float e1 = __uint_as_float(xw[h] & 0xffff0000u);
                float q0 = __uint_as_float(pw[h] << 16);
                float q1 = __uint_as_float(pw[h] & 0xffff0000u);
                d = fmaf(e0, q0, fmaf(e1, q1, d));
            }
        }
        d += __shfl_xor(d, 16, 64); d += __shfl_xor(d, 32, 64);
        if (lq == 0) {
            int row = tile * 16 + lr;
            if (isP) Cp1[b * 128 + row] = d;
            else     Cv[b * 128 + row] = d;
        }
    } else {
        // Spg / Spg2: wave wv handles b = wv
        int b = wv;
        const unsigned short* pgr = xb16 + ((size_t)b * XROWS + 256) * 768;
        float s1 = 0.f, sq = 0.f;
#pragma unroll
        for (int s = 0; s < 12; s++) {
            unsigned x = *(const unsigned*)(pgr + (lane + 64 * s) * 0 + lane * 2 + s * 128);
            // note: read 2 bf16 per lane per step: offset = s*128 + lane*2
            float e0 = __uint_as_float(x << 16);
            float e1 = __uint_as_float(x & 0xffff0000u);
            s1 += e0 + e1;
            sq = fmaf(e0, e0, fmaf(e1, e1, sq));
        }
#pragma unroll
        for (int off = 32; off > 0; off >>= 1) {
            s1 += __shfl_xor(s1, off, 64);
            sq += __shfl_xor(sq, off, 64);
        }
        if (lane == 0) { Spg[b] = s1; Spg2[b] = sq; }
    }
}

// ---------------------------------------------------------------------------
// kC v6: pass-2 only. Stats assembled from decomposed terms.
// Zero LDS/barriers; 1-wave blocks, grid (128,4,8).
// ---------------------------------------------------------------------------
__global__ __launch_bounds__(64, 4) void kC(const unsigned short* __restrict__ xb16,
                                            const unsigned short* __restrict__ vpack,
                                            const float* __restrict__ ln_g,
                                            const float* __restrict__ ln_b,
                                            const unsigned short* __restrict__ rwb16,
                                            const float* __restrict__ rel_b,
                                            const float* __restrict__ mask,
                                            const float* __restrict__ Dp,
                                            const float* __restrict__ Sp1,
                                            const float* __restrict__ Sp1q,
                                            const float* __restrict__ Sv1,
                                            const float* __restrict__ Sv2,
                                            const float* __restrict__ Spg,
                                            const float* __restrict__ Spg2,
                                            const float* __restrict__ Cp1,
                                            const float* __restrict__ Cv,
                                            float* __restrict__ out) {
    int i = blockIdx.x, b = blockIdx.y, jg = blockIdx.z;
    int lane = threadIdx.x;
    int lr = lane & 15, lh = lane >> 4;
    int j = jg * 16 + lr;

    float s1 = Sp1[b * 128 + i] + Spg[b] + Sv1[b * 128 + j];
    float s2 = Sp1q[b * 128 + i] + Spg2[b] + Sv2[b * 128 + j]
             + 2.f * (Dp[((size_t)b * 128 + i) * 128 + j]
                      + Cp1[b * 128 + i] + Cv[b * 128 + j]);
    float mu  = s1 * (1.f / 768.f);
    float rs  = rsqrtf(s2 * (1.f / 768.f) - mu * mu + LN_EPS);
    float nmr = -mu * rs;

    const unsigned short* p1r = xb16 + ((size_t)b * XROWS + i) * 768;
    const unsigned short* pgr = xb16 + ((size_t)b * XROWS + 256) * 768;
    const unsigned short* vfr = vpack + (((size_t)(b * 8 + jg) * 24) * 64 + (size_t)lane) * 8;

    f32x4 acc0 = {0.f, 0.f, 0.f, 0.f}, acc1 = {0.f, 0.f, 0.f, 0.f};
#pragma unroll 2
    for (int s = 0; s < 24; s++) {
        int k = s * 32 + lh * 8;
        uint4 vv = *(const uint4*)(vfr + (size_t)s * 512);
        uint4 uu = *(const uint4*)(p1r + k);
        uint4 pp = *(const uint4*)(pgr + k);
        float4 g0 = *(const float4*)(ln_g + k), g1 = *(const float4*)(ln_g + k + 4);
        float4 b0 = *(const float4*)(ln_b + k), b1 = *(const float4*)(ln_b + k + 4);
        const unsigned* vw = (const unsigned*)&vv;
        const unsigned* uw = (const unsigned*)&uu;
        const unsigned* pw = (const unsigned*)&pp;
        float ge[8] = {g0.x, g0.y, g0.z, g0.w, g1.x, g1.y, g1.z, g1.w};
        float be[8] = {b0.x, b0.y, b0.z, b0.w, b1.x, b1.y, b1.z, b1.w};
        short8 a;
#pragma unroll
        for (int h = 0; h < 4; h++) {
            float z0 = __uint_as_float(vw[h] << 16) + __uint_as_float(uw[h] << 16)
                     + __uint_as_float(pw[h] << 16);
            float z1 = __uint_as_float(vw[h] & 0xffff0000u) + __uint_as_float(uw[h] & 0xffff0000u)
                     + __uint_as_float(pw[h] & 0xffff0000u);
            float t0 = fmaf(fmaf(z0, rs, nmr), ge[2 * h], be[2 * h]);
            float t1 = fmaf(fmaf(z1, rs, nmr), ge[2 * h + 1], be[2 * h + 1]);
            t0 = fmaxf(t0, __expf(fminf(t0, 0.f)) - 1.f);
            t1 = fmaxf(t1, __expf(fminf(t1, 0.f)) - 1.f);
            a[2 * h]     = (short)f2b(t0);
            a[2 * h + 1] = (short)f2b(t1);
        }
        short8 bf0 = *(const short8*)(rwb16 + ((size_t)s * 64 + lane) * 8);
        short8 bf1 = *(const short8*)(rwb16 + ((size_t)(24 + s) * 64 + lane) * 8);
        acc0 = __builtin_amdgcn_mfma_f32_16x16x32_bf16(a, bf0, acc0, 0, 0, 0);
        acc1 = __builtin_amdgcn_mfma_f32_16x16x32_bf16(a, bf1, acc1, 0, 0, 0);
    }

    float mi_ = mask[i * 4 + b];
#pragma unroll
    for (int q = 0; q < 4; q++) {
        int jglob = jg * 16 + lh * 4 + q;
        float mval = mi_ * mask[jglob * 4 + b];
        size_t ob = ((size_t)(i * 128 + jglob) * 4 + b) * 24;
        out[ob + lr] = mval / (1.f + __expf(-(acc0[q] + rel_b[lr])));
        if (lr < 8)
            out[ob + 16 + lr] = mval / (1.f + __expf(-(acc1[q] + rel_b[16 + lr])));
    }
}

// ---------------------------------------------------------------------------
extern "C" void kernel_launch(void* const* d_in, const int* in_sizes, int n_in,
                              void* d_out, int out_size, void* d_ws, size_t ws_size,
                              hipStream_t stream) {
    const float* h_re    = (const float*)d_in[0];
    const float* h_share = (const float*)d_in[1];
    const float* mask    = (const float*)d_in[2];
    const float* r_w     = (const float*)d_in[3];
    const float* r_b     = (const float*)d_in[4];
    const float* hid_w   = (const float*)d_in[5];
    const float* hid_b   = (const float*)d_in[6];
    const float* ln_g    = (const float*)d_in[7];
    const float* ln_b    = (const float*)d_in[8];
    const float* rel_w   = (const float*)d_in[9];
    const float* rel_b   = (const float*)d_in[10];
    float* out = (float*)d_out;

    float* ws = (float*)d_ws;
    unsigned short* apack  = (unsigned short*)(ws);             // 393216 f
    unsigned short* wpackA = (unsigned short*)(ws + 393216);    // 589824 f
    unsigned short* wpackB = (unsigned short*)(ws + 983040);    // 589824 f
    unsigned short* xb16   = (unsigned short*)(ws + 1572864);   // 417792 f
    unsigned short* vpack  = (unsigned short*)(ws + 1990656);   // 196608 f
    unsigned short* p1pack = (unsigned short*)(ws + 2187264);   // 196608 f
    float*          Dp     = ws + 2383872;                      // 65536 f
    unsigned int*   gmax   = (unsigned int*)(ws + 2449408);     // 3072
    unsigned short* rwb16  = (unsigned short*)(ws + 2452480);   // 12288 f
    float*          Sp1    = ws + 2464768;                      // 512
    float*          Sp1q   = ws + 2465280;                      // 512
    float*          Sv1    = ws + 2465792;                      // 512
    float*          Sv2    = ws + 2466304;                      // 512
    float*          Cp1    = ws + 2466816;                      // 512
    float*          Cv     = ws + 2467328;                      // 512
    float*          SpgB   = ws + 2467840;                      // 4
    float*          Spg2B  = ws + 2467844;                      // 4

    kConv<<<1552, 256, 0, stream>>>(h_re, h_share, r_w, hid_w, rel_w,
                                    apack, wpackA, wpackB, rwb16, gmax);
    kGemm<<<1152, 256, 0, stream>>>(apack, wpackA, wpackB, gmax, xb16,
                                    vpack, p1pack);
    kPg<<<dim3(12, 4), 256, 0, stream>>>(gmax, r_b, hid_w, hid_b, xb16);
    kDotS<<<97, 256, 0, stream>>>(p1pack, vpack, xb16, Dp, Sp1, Sp1q,
                                  Sv1, Sv2, Cp1, Cv, SpgB, Spg2B);
    kC<<<dim3(128, 4, 8), 64, 0, stream>>>(xb16, vpack, ln_g, ln_b, rwb16,
                                           rel_b, mask, Dp, Sp1, Sp1q,
                                           Sv1, Sv2, SpgB, Spg2B, Cp1, Cv, out);
}

// Round 21
// 69.108 us; speedup vs baseline: 2.0121x; 1.0193x over previous
//
#include <hip/hip_runtime.h>
#include <hip/hip_bf16.h>
#include <math.h>

#define L 128
#define B 4
#define H 768
#define LN_EPS 1e-5f
#define XROWS 272            // xb16 rows: [p1:0..127 | unused | pg:256 | tail]

typedef __attribute__((ext_vector_type(8))) short short8;
typedef __attribute__((ext_vector_type(4))) float f32x4;

static __device__ __forceinline__ unsigned f2bfu(float f) {
    unsigned u = __float_as_uint(f);
    return (u + 0x7FFFu + ((u >> 16) & 1u)) >> 16;
}
static __device__ __forceinline__ uint2 pk4(float4 v) {
    uint2 o;
    o.x = f2bfu(v.x) | (f2bfu(v.y) << 16);
    o.y = f2bfu(v.z) | (f2bfu(v.w) << 16);
    return o;
}
static __device__ __forceinline__ unsigned short f2b(float f) {
    union { __hip_bfloat16 h; unsigned short u; } cv;
    cv.h = __float2bfloat16(f);
    return cv.u;
}
static __device__ __forceinline__ unsigned fkey(float x) {
    unsigned u = __float_as_uint(x);
    return (u >> 31) ? ~u : (u | 0x80000000u);
}

// ---------------------------------------------------------------------------
// kConv: all fp32->bf16 packing, coalesced READS + scattered 16B writes.
// ---------------------------------------------------------------------------
__global__ __launch_bounds__(256) void kConv(const float* __restrict__ h_re,
                                             const float* __restrict__ h_share,
                                             const float* __restrict__ r_w,
                                             const float* __restrict__ hid_w,
                                             const float* __restrict__ rel_w,
                                             unsigned short* __restrict__ apack,
                                             unsigned short* __restrict__ wpackA,
                                             unsigned short* __restrict__ wpackB,
                                             unsigned short* __restrict__ rwb16,
                                             unsigned int* __restrict__ gmax) {
    int t = blockIdx.x * 256 + threadIdx.x;
    if (t >= 397056) return;
    if (t < 98304) {                          // apack: Acat=[h_share|h_re]
        int m = t / 192, oct = t % 192, k = oct * 8;
        const float* src = (k < 768) ? (h_share + (size_t)m * 768 + k)
                                     : (h_re + (size_t)m * 768 + k - 768);
        float4 x = *(const float4*)src, y = *(const float4*)(src + 4);
        int mt = m >> 4, lr = m & 15, ks = k >> 5, lq = (k >> 3) & 3;
        uint2* dst = (uint2*)(apack + (((size_t)mt * 48 + ks) * 64 + lq * 16 + lr) * 8);
        dst[0] = pk4(x); dst[1] = pk4(y);
    } else if (t < 245760) {                  // wpackA: r_w rows
        int t2 = t - 98304;
        int n = t2 / 192, oct = t2 % 192, k = oct * 8;
        const float* src = r_w + (size_t)n * 1536 + k;
        float4 x = *(const float4*)src, y = *(const float4*)(src + 4);
        int nt = n >> 4, lr = n & 15, ks = k >> 5, lq = (k >> 3) & 3;
        uint2* dst = (uint2*)(wpackA + (((size_t)nt * 48 + ks) * 64 + lq * 16 + lr) * 8);
        dst[0] = pk4(x); dst[1] = pk4(y);
    } else if (t < 393216) {                  // wpackB: hid_w rows (w1|w2)
        int t3 = t - 245760;
        int n = t3 / 96, oct = t3 % 96, k = oct * 8;
        int half = (n >= 768) ? 1 : 0;
        const float* src = hid_w + (size_t)(n - half * 768) * 2304 + half * 768 + k;
        float4 x = *(const float4*)src, y = *(const float4*)(src + 4);
        int nt = n >> 4, lr = n & 15, ks = k >> 5, lq = (k >> 3) & 3;
        uint2* dst = (uint2*)(wpackB + (((size_t)nt * 24 + ks) * 64 + lq * 16 + lr) * 8);
        dst[0] = pk4(x); dst[1] = pk4(y);
    } else if (t < 396288) {                  // rwb16 B-frags (16x16x32), zero-pad r>=24
        int t4 = t - 393216;
        int nt = t4 / 1536, ks = (t4 / 64) % 24, l = t4 & 63;
        int row = nt * 16 + (l & 15);
        int k = ks * 32 + (l >> 4) * 8;
        uint2 o0 = make_uint2(0u, 0u), o1 = o0;
        if (row < 24) {
            const float* src = rel_w + (size_t)row * 768 + k;
            o0 = pk4(*(const float4*)src);
            o1 = pk4(*(const float4*)(src + 4));
        }
        uint2* dst = (uint2*)(rwb16 + (size_t)t4 * 8);
        dst[0] = o0; dst[1] = o1;
    } else {                                  // gmax zero (768 scalars)
        int t6 = t - 396288;
        gmax[t6] = 0u;
        gmax[768 + t6] = 0u;
        gmax[1536 + t6] = 0u;
        gmax[2304 + t6] = 0u;
    }
}

// ---------------------------------------------------------------------------
// gemm_steps: shared MFMA inner loop (frag-linear operands, stride 512/step).
// ---------------------------------------------------------------------------
template<int KSW>
static __device__ __forceinline__ void gemm_steps(const unsigned short* __restrict__ a0p,
                                                  const unsigned short* __restrict__ a1p,
                                                  const unsigned short* __restrict__ w0p,
                                                  const unsigned short* __restrict__ w1p,
                                                  f32x4 acc[2][2]) {
#pragma unroll
    for (int s = 0; s < KSW; s++) {
        short8 a0 = *(const short8*)(a0p + (size_t)s * 512);
        short8 a1 = *(const short8*)(a1p + (size_t)s * 512);
        short8 w0 = *(const short8*)(w0p + (size_t)s * 512);
        short8 w1 = *(const short8*)(w1p + (size_t)s * 512);
        acc[0][0] = __builtin_amdgcn_mfma_f32_16x16x32_bf16(a0, w0, acc[0][0], 0, 0, 0);
        acc[0][1] = __builtin_amdgcn_mfma_f32_16x16x32_bf16(a0, w1, acc[0][1], 0, 0, 0);
        acc[1][0] = __builtin_amdgcn_mfma_f32_16x16x32_bf16(a1, w0, acc[1][0], 0, 0, 0);
        acc[1][1] = __builtin_amdgcn_mfma_f32_16x16x32_bf16(a1, w1, acc[1][1], 0, 0, 0);
    }
}

// ---------------------------------------------------------------------------
// kGemm: 4-wave blocks, one 32x32 tile, K split 4 ways, LDS reduce (r13).
// B-part epilogue: p2 -> vpack; p1 -> xb16 row-major AND p1pack.
// ---------------------------------------------------------------------------
__global__ __launch_bounds__(256) void kGemm(const unsigned short* __restrict__ apack,
                                             const unsigned short* __restrict__ wpackA,
                                             const unsigned short* __restrict__ wpackB,
                                             unsigned int* __restrict__ gmax,
                                             unsigned short* __restrict__ xb16,
                                             unsigned short* __restrict__ vpack,
                                             unsigned short* __restrict__ p1pack) {
    __shared__ float red[4][4][64][4];        // 16 KB
    int id = blockIdx.x;
    int tid = threadIdx.x, lane = tid & 63, wv = tid >> 6;
    int lq = lane >> 4, lr = lane & 15;
    bool isA = id < 384;
    f32x4 acc[2][2] = {{{0.f,0.f,0.f,0.f},{0.f,0.f,0.f,0.f}},
                       {{0.f,0.f,0.f,0.f},{0.f,0.f,0.f,0.f}}};
    int mt0, nt0;
    if (isA) {
        mt0 = (id / 24) * 2; nt0 = (id % 24) * 2;
        const unsigned short* a0p = apack + ((size_t)mt0 * 48 + wv * 12) * 512 + lane * 8;
        const unsigned short* w0p = wpackA + ((size_t)nt0 * 48 + wv * 12) * 512 + lane * 8;
        gemm_steps<12>(a0p, a0p + 48 * 512, w0p, w0p + 48 * 512, acc);
    } else {
        int id2 = id - 384;
        mt0 = (id2 / 48) * 2; nt0 = (id2 % 48) * 2;
        const unsigned short* a0p = apack + ((size_t)mt0 * 48 + 24 + wv * 6) * 512 + lane * 8;
        const unsigned short* w0p = wpackB + ((size_t)nt0 * 24 + wv * 6) * 512 + lane * 8;
        gemm_steps<6>(a0p, a0p + 48 * 512, w0p, w0p + 24 * 512, acc);
    }
#pragma unroll
    for (int mi = 0; mi < 2; mi++)
#pragma unroll
        for (int ni = 0; ni < 2; ni++)
            *(f32x4*)&red[wv][mi * 2 + ni][lane][0] = acc[mi][ni];
    __syncthreads();
    if (wv != 0) return;

    f32x4 s2[2][2];
#pragma unroll
    for (int mi = 0; mi < 2; mi++)
#pragma unroll
        for (int ni = 0; ni < 2; ni++) {
            f32x4 v = *(f32x4*)&red[0][mi * 2 + ni][lane][0];
#pragma unroll
            for (int w = 1; w < 4; w++) {
                f32x4 u = *(f32x4*)&red[w][mi * 2 + ni][lane][0];
                v[0] += u[0]; v[1] += u[1]; v[2] += u[2]; v[3] += u[3];
            }
            s2[mi][ni] = v;
        }

    if (isA) {
#pragma unroll
        for (int ni = 0; ni < 2; ni++)
#pragma unroll
            for (int q = 0; q < 4; q++) {
                float mx = fmaxf(s2[0][ni][q], s2[1][ni][q]);
                mx = fmaxf(mx, __shfl_xor(mx, 16, 64));
                mx = fmaxf(mx, __shfl_xor(mx, 32, 64));
                if (lq == 0) {
                    int n = (nt0 + ni) * 16 + lr;
                    atomicMax(&gmax[q * 768 + n], fkey(mx));
                }
            }
    } else {
#pragma unroll
        for (int mi = 0; mi < 2; mi++)
#pragma unroll
            for (int ni = 0; ni < 2; ni++)
#pragma unroll
                for (int q = 0; q < 4; q++) {
                    int m = (mt0 + mi) * 16 + lq * 4 + q;
                    int n = (nt0 + ni) * 16 + lr;
                    int b = m & 3, l = m >> 2;
                    unsigned short val = f2b(s2[mi][ni][q]);
                    if (n < 768) {
                        xb16[((size_t)b * XROWS + l) * 768 + n] = val;
                        size_t dst = ((((size_t)(b * 8 + (l >> 4)) * 24) + (n >> 5)) * 64
                                      + ((n >> 3) & 3) * 16 + (l & 15)) * 8 + (n & 7);
                        p1pack[dst] = val;
                    } else {
                        int k = n - 768;
                        size_t dst = ((((size_t)(b * 8 + (l >> 4)) * 24) + (k >> 5)) * 64
                                      + ((k >> 3) & 3) * 16 + (l & 15)) * 8 + (k & 7);
                        vpack[dst] = val;
                    }
                }
    }
}

// ---------------------------------------------------------------------------
// kPg (r13-proven): grid (12,4), 48 blocks. tanh decode + pg GEMM + bf16 write.
// ---------------------------------------------------------------------------
__global__ __launch_bounds__(256) void kPg(const unsigned int* __restrict__ gmax,
                                           const float* __restrict__ r_b,
                                           const float* __restrict__ hid_w,
                                           const float* __restrict__ hid_b,
                                           unsigned short* __restrict__ xb16) {
    __shared__ float sg[768];
    __shared__ float sp[4][64];
    int kt = blockIdx.x, b = blockIdx.y, tid = threadIdx.x;
    for (int v = tid; v < 768; v += 256) {
        unsigned key = gmax[b * 768 + v];
        unsigned bits = (key & 0x80000000u) ? (key & 0x7FFFFFFFu) : ~key;
        sg[v] = tanhf(__uint_as_float(bits) + r_b[v]);
    }
    __syncthreads();
    int kk = tid & 63, hc = tid >> 6;
    int k = kt * 64 + kk;
    const float4* w4 = (const float4*)hid_w;
    const float4* g4 = (const float4*)sg;
    float acc = 0.f;
    for (int h = hc * 48; h < hc * 48 + 48; h++) {
        float4 gv = g4[h];
        float4 wv = w4[(size_t)k * 576 + 384 + h];
        acc += gv.x * wv.x + gv.y * wv.y + gv.z * wv.z + gv.w * wv.w;
    }
    sp[hc][kk] = acc;
    __syncthreads();
    if (hc == 0) {
        float pgv = sp[0][kk] + sp[1][kk] + sp[2][kk] + sp[3][kk] + hid_b[k];
        xb16[((size_t)b * XROWS + 256) * 768 + k] = f2b(pgv);
    }
}

// ---------------------------------------------------------------------------
// kDotS (97 blocks, after kPg):
//  0..63 : Dp[b][i][j] = dot(p1_i, v_j) via MFMA 32x32 tiles (K/4 + LDS reduce)
//  64..79: per-row sums/sumsq of p1 and v (frag reads + 2-shfl reduce)
//  80..95: cross dots Cp1[i]=dot(pg,p1_i), Cv[j]=dot(pg,v_j)
//  96    : Spg/Spg2 per b (one wave each; 768 shorts = lane*2 + s*128, s<6)
// ---------------------------------------------------------------------------
__global__ __launch_bounds__(256) void kDotS(const unsigned short* __restrict__ p1pack,
                                             const unsigned short* __restrict__ vpack,
                                             const unsigned short* __restrict__ xb16,
                                             float* __restrict__ Dp,
                                             float* __restrict__ Sp1,
                                             float* __restrict__ Sp1q,
                                             float* __restrict__ Sv1,
                                             float* __restrict__ Sv2,
                                             float* __restrict__ Cp1,
                                             float* __restrict__ Cv,
                                             float* __restrict__ Spg,
                                             float* __restrict__ Spg2) {
    __shared__ float red[4][4][64][4];
    int id = blockIdx.x;
    int tid = threadIdx.x, lane = tid & 63, wv = tid >> 6;
    int lq = lane >> 4, lr = lane & 15;
    if (id < 64) {
        int b = id >> 4, tile = id & 15, it = tile >> 2, jt = tile & 3;
        f32x4 acc[2][2] = {{{0.f,0.f,0.f,0.f},{0.f,0.f,0.f,0.f}},
                           {{0.f,0.f,0.f,0.f},{0.f,0.f,0.f,0.f}}};
        const unsigned short* a0p = p1pack + (((size_t)(b * 8 + it * 2) * 24) + wv * 6) * 512 + lane * 8;
        const unsigned short* a1p = p1pack + (((size_t)(b * 8 + it * 2 + 1) * 24) + wv * 6) * 512 + lane * 8;
        const unsigned short* w0p = vpack + (((size_t)(b * 8 + jt * 2) * 24) + wv * 6) * 512 + lane * 8;
        const unsigned short* w1p = vpack + (((size_t)(b * 8 + jt * 2 + 1) * 24) + wv * 6) * 512 + lane * 8;
        gemm_steps<6>(a0p, a1p, w0p, w1p, acc);
#pragma unroll
        for (int mi = 0; mi < 2; mi++)
#pragma unroll
            for (int ni = 0; ni < 2; ni++)
                *(f32x4*)&red[wv][mi * 2 + ni][lane][0] = acc[mi][ni];
        __syncthreads();
        if (wv != 0) return;
#pragma unroll
        for (int mi = 0; mi < 2; mi++)
#pragma unroll
            for (int ni = 0; ni < 2; ni++) {
                f32x4 v = *(f32x4*)&red[0][mi * 2 + ni][lane][0];
#pragma unroll
                for (int w = 1; w < 4; w++) {
                    f32x4 u = *(f32x4*)&red[w][mi * 2 + ni][lane][0];
                    v[0] += u[0]; v[1] += u[1]; v[2] += u[2]; v[3] += u[3];
                }
#pragma unroll
                for (int q = 0; q < 4; q++) {
                    int i = it * 32 + mi * 16 + lq * 4 + q;
                    int j = jt * 32 + ni * 16 + lr;
                    Dp[((size_t)b * 128 + i) * 128 + j] = v[q];
                }
            }
    } else if (id < 80) {
        int t = (id - 64) * 4 + wv;            // 0..63
        bool isP = t < 32;
        int t2 = t & 31;
        int b = t2 >> 3, tile = t2 & 7;
        const unsigned short* src = (isP ? p1pack : vpack)
                                    + ((size_t)(b * 8 + tile) * 24) * 512 + lane * 8;
        float s1 = 0.f, sq = 0.f;
        for (int s = 0; s < 24; s++) {
            uint4 x = *(const uint4*)(src + (size_t)s * 512);
            const unsigned* xw = (const unsigned*)&x;
#pragma unroll
            for (int h = 0; h < 4; h++) {
                float e0 = __uint_as_float(xw[h] << 16);
                float e1 = __uint_as_float(xw[h] & 0xffff0000u);
                s1 += e0 + e1;
                sq = fmaf(e0, e0, fmaf(e1, e1, sq));
            }
        }
        s1 += __shfl_xor(s1, 16, 64); s1 += __shfl_xor(s1, 32, 64);
        sq += __shfl_xor(sq, 16, 64); sq += __shfl_xor(sq, 32, 64);
        if (lq == 0) {
            int row = tile * 16 + lr;
            if (isP) { Sp1[b * 128 + row] = s1; Sp1q[b * 128 + row] = sq; }
            else     { Sv1[b * 128 + row] = s1; Sv2[b * 128 + row] = sq; }
        }
    } else if (id < 96) {
        int t = (id - 80) * 4 + wv;            // 0..63
        bool isP = t < 32;
        int t2 = t & 31;
        int b = t2 >> 3, tile = t2 & 7;
        const unsigned short* src = (isP ? p1pack : vpack)
                                    + ((size_t)(b * 8 + tile) * 24) * 512 + lane * 8;
        const unsigned short* pgr = xb16 + ((size_t)b * XROWS + 256) * 768;
        float d = 0.f;
        for (int s = 0; s < 24; s++) {
            int kb = s * 32 + lq * 8;
            uint4 x = *(const uint4*)(src + (size_t)s * 512);
            uint4 p = *(const uint4*)(pgr + kb);
            const unsigned* xw = (const unsigned*)&x;
            const unsigned* pw = (const unsigned*)&p;
#pragma unroll
            for (int h = 0; h < 4; h++) {
                float e0 = __uint_as_float(xw[h] << 16);
                float e1 = __uint_as_float(xw[h] & 0xffff0000u);
                float q0 = __uint_as_float(pw[h] << 16);
                float q1 = __uint_as_float(pw[h] & 0xffff0000u);
                d = fmaf(e0, q0, fmaf(e1, q1, d));
            }
        }
        d += __shfl_xor(d, 16, 64); d += __shfl_xor(d, 32, 64);
        if (lq == 0) {
            int row = tile * 16 + lr;
            if (isP) Cp1[b * 128 + row] = d;
            else     Cv[b * 128 + row] = d;
        }
    } else {
        // Spg / Spg2: wave wv handles b = wv. 768 shorts = 64 lanes x 2 x 6.
        int b = wv;
        const unsigned short* pgr = xb16 + ((size_t)b * XROWS + 256) * 768;
        float s1 = 0.f, sq = 0.f;
#pragma unroll
        for (int s = 0; s < 6; s++) {
            unsigned x = *(const unsigned*)(pgr + lane * 2 + s * 128);
            float e0 = __uint_as_float(x << 16);
            float e1 = __uint_as_float(x & 0xffff0000u);
            s1 += e0 + e1;
            sq = fmaf(e0, e0, fmaf(e1, e1, sq));
        }
#pragma unroll
        for (int off = 32; off > 0; off >>= 1) {
            s1 += __shfl_xor(s1, off, 64);
            sq += __shfl_xor(sq, off, 64);
        }
        if (lane == 0) { Spg[b] = s1; Spg2[b] = sq; }
    }
}

// ---------------------------------------------------------------------------
// kC v7: 2-wave blocks, K split across waves (wave w: steps 12w..12w+11),
// 2KB LDS partial reduce, wave-0 epilogue. Grid (128,4,8) x 128 thr =
// 8192 waves = 32 waves/CU (r20's 4096 waves = 16/CU = the latency exposure).
// Stats from decomposed terms (kDotS).
// ---------------------------------------------------------------------------
__global__ __launch_bounds__(128, 4) void kC(const unsigned short* __restrict__ xb16,
                                             const unsigned short* __restrict__ vpack,
                                             const float* __restrict__ ln_g,
                                             const float* __restrict__ ln_b,
                                             const unsigned short* __restrict__ rwb16,
                                             const float* __restrict__ rel_b,
                                             const float* __restrict__ mask,
                                             const float* __restrict__ Dp,
                                             const float* __restrict__ Sp1,
                                             const float* __restrict__ Sp1q,
                                             const float* __restrict__ Sv1,
                                             const float* __restrict__ Sv2,
                                             const float* __restrict__ Spg,
                                             const float* __restrict__ Spg2,
                                             const float* __restrict__ Cp1,
                                             const float* __restrict__ Cv,
                                             float* __restrict__ out) {
    __shared__ float red[2][64][4];           // wave1 partials, 2 KB
    int i = blockIdx.x, b = blockIdx.y, jg = blockIdx.z;
    int tid = threadIdx.x, lane = tid & 63, wv = tid >> 6;
    int lr = lane & 15, lh = lane >> 4;
    int j = jg * 16 + lr;

    float s1 = Sp1[b * 128 + i] + Spg[b] + Sv1[b * 128 + j];
    float s2 = Sp1q[b * 128 + i] + Spg2[b] + Sv2[b * 128 + j]
             + 2.f * (Dp[((size_t)b * 128 + i) * 128 + j]
                      + Cp1[b * 128 + i] + Cv[b * 128 + j]);
    float mu  = s1 * (1.f / 768.f);
    float rs  = rsqrtf(s2 * (1.f / 768.f) - mu * mu + LN_EPS);
    float nmr = -mu * rs;

    const unsigned short* p1r = xb16 + ((size_t)b * XROWS + i) * 768;
    const unsigned short* pgr = xb16 + ((size_t)b * XROWS + 256) * 768;
    const unsigned short* vfr = vpack + (((size_t)(b * 8 + jg) * 24) * 64 + (size_t)lane) * 8;

    f32x4 acc0 = {0.f, 0.f, 0.f, 0.f}, acc1 = {0.f, 0.f, 0.f, 0.f};
    int sbase = wv * 12;
#pragma unroll 2
    for (int ss = 0; ss < 12; ss++) {
        int s = sbase + ss;
        int k = s * 32 + lh * 8;
        uint4 vv = *(const uint4*)(vfr + (size_t)s * 512);
        uint4 uu = *(const uint4*)(p1r + k);
        uint4 pp = *(const uint4*)(pgr + k);
        float4 g0 = *(const float4*)(ln_g + k), g1 = *(const float4*)(ln_g + k + 4);
        float4 b0 = *(const float4*)(ln_b + k), b1 = *(const float4*)(ln_b + k + 4);
        const unsigned* vw = (const unsigned*)&vv;
        const unsigned* uw = (const unsigned*)&uu;
        const unsigned* pw = (const unsigned*)&pp;
        float ge[8] = {g0.x, g0.y, g0.z, g0.w, g1.x, g1.y, g1.z, g1.w};
        float be[8] = {b0.x, b0.y, b0.z, b0.w, b1.x, b1.y, b1.z, b1.w};
        short8 a;
#pragma unroll
        for (int h = 0; h < 4; h++) {
            float z0 = __uint_as_float(vw[h] << 16) + __uint_as_float(uw[h] << 16)
                     + __uint_as_float(pw[h] << 16);
            float z1 = __uint_as_float(vw[h] & 0xffff0000u) + __uint_as_float(uw[h] & 0xffff0000u)
                     + __uint_as_float(pw[h] & 0xffff0000u);
            float t0 = fmaf(fmaf(z0, rs, nmr), ge[2 * h], be[2 * h]);
            float t1 = fmaf(fmaf(z1, rs, nmr), ge[2 * h + 1], be[2 * h + 1]);
            t0 = fmaxf(t0, __expf(fminf(t0, 0.f)) - 1.f);
            t1 = fmaxf(t1, __expf(fminf(t1, 0.f)) - 1.f);
            a[2 * h]     = (short)f2b(t0);
            a[2 * h + 1] = (short)f2b(t1);
        }
        short8 bf0 = *(const short8*)(rwb16 + ((size_t)s * 64 + lane) * 8);
        short8 bf1 = *(const short8*)(rwb16 + ((size_t)(24 + s) * 64 + lane) * 8);
        acc0 = __builtin_amdgcn_mfma_f32_16x16x32_bf16(a, bf0, acc0, 0, 0, 0);
        acc1 = __builtin_amdgcn_mfma_f32_16x16x32_bf16(a, bf1, acc1, 0, 0, 0);
    }

    if (wv == 1) {
        *(f32x4*)&red[0][lane][0] = acc0;
        *(f32x4*)&red[1][lane][0] = acc1;
    }
    __syncthreads();
    if (wv != 0) return;
    f32x4 o0 = *(f32x4*)&red[0][lane][0];
    f32x4 o1 = *(f32x4*)&red[1][lane][0];
    acc0[0] += o0[0]; acc0[1] += o0[1]; acc0[2] += o0[2]; acc0[3] += o0[3];
    acc1[0] += o1[0]; acc1[1] += o1[1]; acc1[2] += o1[2]; acc1[3] += o1[3];

    float mi_ = mask[i * 4 + b];
#pragma unroll
    for (int q = 0; q < 4; q++) {
        int jglob = jg * 16 + lh * 4 + q;
        float mval = mi_ * mask[jglob * 4 + b];
        size_t ob = ((size_t)(i * 128 + jglob) * 4 + b) * 24;
        out[ob + lr] = mval / (1.f + __expf(-(acc0[q] + rel_b[lr])));
        if (lr < 8)
            out[ob + 16 + lr] = mval / (1.f + __expf(-(acc1[q] + rel_b[16 + lr])));
    }
}

// ---------------------------------------------------------------------------
extern "C" void kernel_launch(void* const* d_in, const int* in_sizes, int n_in,
                              void* d_out, int out_size, void* d_ws, size_t ws_size,
                              hipStream_t stream) {
    const float* h_re    = (const float*)d_in[0];
    const float* h_share = (const float*)d_in[1];
    const float* mask    = (const float*)d_in[2];
    const float* r_w     = (const float*)d_in[3];
    const float* r_b     = (const float*)d_in[4];
    const float* hid_w   = (const float*)d_in[5];
    const float* hid_b   = (const float*)d_in[6];
    const float* ln_g    = (const float*)d_in[7];
    const float* ln_b    = (const float*)d_in[8];
    const float* rel_w   = (const float*)d_in[9];
    const float* rel_b   = (const float*)d_in[10];
    float* out = (float*)d_out;

    float* ws = (float*)d_ws;
    unsigned short* apack  = (unsigned short*)(ws);             // 393216 f
    unsigned short* wpackA = (unsigned short*)(ws + 393216);    // 589824 f
    unsigned short* wpackB = (unsigned short*)(ws + 983040);    // 589824 f
    unsigned short* xb16   = (unsigned short*)(ws + 1572864);   // 417792 f
    unsigned short* vpack  = (unsigned short*)(ws + 1990656);   // 196608 f
    unsigned short* p1pack = (unsigned short*)(ws + 2187264);   // 196608 f
    float*          Dp     = ws + 2383872;                      // 65536 f
    unsigned int*   gmax   = (unsigned int*)(ws + 2449408);     // 3072
    unsigned short* rwb16  = (unsigned short*)(ws + 2452480);   // 12288 f
    float*          Sp1    = ws + 2464768;                      // 512
    float*          Sp1q   = ws + 2465280;                      // 512
    float*          Sv1    = ws + 2465792;                      // 512
    float*          Sv2    = ws + 2466304;                      // 512
    float*          Cp1    = ws + 2466816;                      // 512
    float*          Cv     = ws + 2467328;                      // 512
    float*          SpgB   = ws + 2467840;                      // 4
    float*          Spg2B  = ws + 2467844;                      // 4

    kConv<<<1552, 256, 0, stream>>>(h_re, h_share, r_w, hid_w, rel_w,
                                    apack, wpackA, wpackB, rwb16, gmax);
    kGemm<<<1152, 256, 0, stream>>>(apack, wpackA, wpackB, gmax, xb16,
                                    vpack, p1pack);
    kPg<<<dim3(12, 4), 256, 0, stream>>>(gmax, r_b, hid_w, hid_b, xb16);
    kDotS<<<97, 256, 0, stream>>>(p1pack, vpack, xb16, Dp, Sp1, Sp1q,
                                  Sv1, Sv2, Cp1, Cv, SpgB, Spg2B);
    kC<<<dim3(128, 4, 8), 128, 0, stream>>>(xb16, vpack, ln_g, ln_b, rwb16,
                                            rel_b, mask, Dp, Sp1, Sp1q,
                                            Sv1, Sv2, SpgB, Spg2B, Cp1, Cv, out);
}